// Round 2
// baseline (605.476 us; speedup 1.0000x reference)
//
#include <hip/hip_runtime.h>
#include <math.h>

#define C 100
#define NTH 21
#define NBINS 22           // bin 21 = "never certain"
#define EPSD 1e-10

// ---------- order-preserving float<->uint encoding for atomic min/max ----------
__device__ __forceinline__ unsigned enc_f(float x){
    unsigned u = __float_as_uint(x);
    return (u & 0x80000000u) ? ~u : (u | 0x80000000u);
}
__device__ __forceinline__ float dec_f(unsigned e){
    unsigned u = (e & 0x80000000u) ? (e ^ 0x80000000u) : ~e;
    return __uint_as_float(u);
}

// ---------- per-row softmax stats; 4 lanes (l=0..3) cooperate on one row ----------
// All 4 lanes return identical (unc, conf). acc valid on l==0 only.
__device__ __forceinline__ void row_compute(const float* __restrict__ rp,
                                            const int* __restrict__ labels,
                                            int row, int l,
                                            float& unc, float& conf, bool& acc){
    const float4* rp4 = (const float4*)rp;        // 400B rows, 16B aligned
    float4 v[6];
    #pragma unroll
    for (int k = 0; k < 6; ++k) v[k] = rp4[l + 4*k];   // cols 16*(l+4k) .. +15 bytes
    float4 v6;
    if (l == 0) v6 = rp4[24];                          // cols 96..99

    float m = -INFINITY;
    #pragma unroll
    for (int k = 0; k < 6; ++k)
        m = fmaxf(m, fmaxf(fmaxf(v[k].x, v[k].y), fmaxf(v[k].z, v[k].w)));
    if (l == 0)
        m = fmaxf(m, fmaxf(fmaxf(v6.x, v6.y), fmaxf(v6.z, v6.w)));
    m = fmaxf(m, __shfl_xor(m, 1, 64));
    m = fmaxf(m, __shfl_xor(m, 2, 64));

    float s = 0.0f, dd = 0.0f;
    #pragma unroll
    for (int k = 0; k < 6; ++k){
        float d0 = v[k].x - m, d1 = v[k].y - m, d2 = v[k].z - m, d3 = v[k].w - m;
        float e0 = __expf(d0), e1 = __expf(d1), e2 = __expf(d2), e3 = __expf(d3);
        s  += (e0 + e1) + (e2 + e3);
        dd += (e0*d0 + e1*d1) + (e2*d2 + e3*d3);
    }
    if (l == 0){
        float d0 = v6.x - m, d1 = v6.y - m, d2 = v6.z - m, d3 = v6.w - m;
        float e0 = __expf(d0), e1 = __expf(d1), e2 = __expf(d2), e3 = __expf(d3);
        s  += (e0 + e1) + (e2 + e3);
        dd += (e0*d0 + e1*d1) + (e2*d2 + e3*d3);
    }
    s  += __shfl_xor(s, 1, 64);   dd += __shfl_xor(dd, 1, 64);
    s  += __shfl_xor(s, 2, 64);   dd += __shfl_xor(dd, 2, 64);

    conf = 1.0f / s;                 // max prob = exp(0)/S
    unc  = __logf(s) - dd / s;       // == -sum p*log(p); eps term ~1e-8, negligible
    acc = false;
    if (l == 0){
        int lbl = labels[row];
        acc = (rp[lbl] == m);        // accurate <=> label's logit achieves the max
    }
}

// ---------- init: zero hist, set min/max identities ----------
__global__ void init_kernel(unsigned* __restrict__ minmax, double* __restrict__ hist){
    if (threadIdx.x == 0){ minmax[0] = 0xFFFFFFFFu; minmax[1] = 0u; }
    if (threadIdx.x < 4*NBINS) hist[threadIdx.x] = 0.0;
}

// ---------- pass 1: stream logits; per-sample {unc, signed conf}; global min/max ----------
template<bool STORE>
__global__ void __launch_bounds__(256) pass1_kernel(const float* __restrict__ logits,
        const int* __restrict__ labels, float2* __restrict__ uc_out,
        unsigned* __restrict__ minmax, int N){
    const int lane = threadIdx.x & 63;
    const int l    = lane & 3;
    const int grp  = lane >> 2;                 // 0..15: 16 rows per wave-iteration
    const int wid  = threadIdx.x >> 6;
    const int gw   = (blockIdx.x * blockDim.x + threadIdx.x) >> 6;
    const int nw   = (gridDim.x * blockDim.x) >> 6;
    const int rowstep = nw * 16;                // rows per sweep

    float rmin = INFINITY, rmax = -INFINITY;
    int row = gw * 16 + grp;
    const float* rp = logits + (size_t)row * C;
    const size_t pstep = (size_t)rowstep * C;
    for (; row < N; row += rowstep, rp += pstep){
        float unc, conf; bool acc;
        row_compute(rp, labels, row, l, unc, conf, acc);
        rmin = fminf(rmin, unc);
        rmax = fmaxf(rmax, unc);
        if (STORE && l == 0)
            uc_out[row] = make_float2(unc, acc ? conf : -conf);  // sign encodes accuracy
    }
    // wave reduce once at end
    #pragma unroll
    for (int off = 1; off < 64; off <<= 1){
        rmin = fminf(rmin, __shfl_xor(rmin, off, 64));
        rmax = fmaxf(rmax, __shfl_xor(rmax, off, 64));
    }
    __shared__ float smin[4], smax[4];
    if (lane == 0){ smin[wid] = rmin; smax[wid] = rmax; }
    __syncthreads();
    if (threadIdx.x == 0){
        float bmin = fminf(fminf(smin[0], smin[1]), fminf(smin[2], smin[3]));
        float bmax = fmaxf(fmaxf(smax[0], smax[1]), fmaxf(smax[2], smax[3]));
        atomicMin(minmax + 0, enc_f(bmin));
        atomicMax(minmax + 1, enc_f(bmax));
    }
}

// ---------- shared bucket/weight accumulation ----------
__device__ __forceinline__ void accumulate_sample(float unc, float conf, bool acc,
                                                  const float* __restrict__ th,
                                                  float* __restrict__ lh){
    // tanh(u) = 1 - 2/(e^{2u}+1); u >= 0 so no overflow (u <= ~4.7 here)
    float tn = 1.0f - 2.0f / (__expf(2.0f * unc) + 1.0f);
    // t0 = first threshold with unc <= th[t]; th monotone -> count trick
    int cnt = 0;
    #pragma unroll
    for (int t = 0; t < NTH; ++t) cnt += (unc <= th[t]) ? 1 : 0;
    int t0 = NTH - cnt;                 // 21 => never certain
    float wcert, wunc; int base;
    if (acc){ wcert = conf * (1.0f - tn);  wunc = conf * tn;  base = 0; }
    else    { float ic = 1.0f - conf;
              wcert = ic * (1.0f - tn);    wunc = ic * tn;    base = 2; }
    atomicAdd(&lh[base * NBINS + t0], wcert);        // ac or ic (certain side, prefix)
    atomicAdd(&lh[(base + 1) * NBINS + t0], wunc);   // au or iu (uncertain side, suffix)
}

// ---------- pass 2 (fast path): read packed scalars, build histogram ----------
__global__ void __launch_bounds__(256) pass2_store_kernel(const float2* __restrict__ uc_in,
        const unsigned* __restrict__ minmax, double* __restrict__ hist, int N){
    __shared__ float th[NTH];
    __shared__ float lh[4 * NBINS];
    float umin = dec_f(minmax[0]);
    float umax = dec_f(minmax[1]);
    if (threadIdx.x < NTH){
        float t = (threadIdx.x == 20) ? 1.0f : (float)threadIdx.x * 0.05f;  // linspace(0,1,21)
        th[threadIdx.x] = umin + t * (umax - umin);
    }
    for (int i = threadIdx.x; i < 4 * NBINS; i += blockDim.x) lh[i] = 0.0f;
    __syncthreads();

    int stride = gridDim.x * blockDim.x;
    for (int i = blockIdx.x * blockDim.x + threadIdx.x; i < N; i += stride){
        float2 s = uc_in[i];
        accumulate_sample(s.x, fabsf(s.y), s.y > 0.0f, th, lh);
    }
    __syncthreads();
    for (int i = threadIdx.x; i < 4 * NBINS; i += blockDim.x)
        atomicAdd(&hist[i], (double)lh[i]);
}

// ---------- pass 2 (fallback): recompute softmax stats (no big workspace) ----------
__global__ void __launch_bounds__(256) pass2_recompute_kernel(const float* __restrict__ logits,
        const int* __restrict__ labels, const unsigned* __restrict__ minmax,
        double* __restrict__ hist, int N){
    __shared__ float th[NTH];
    __shared__ float lh[4 * NBINS];
    float umin = dec_f(minmax[0]);
    float umax = dec_f(minmax[1]);
    if (threadIdx.x < NTH){
        float t = (threadIdx.x == 20) ? 1.0f : (float)threadIdx.x * 0.05f;
        th[threadIdx.x] = umin + t * (umax - umin);
    }
    for (int i = threadIdx.x; i < 4 * NBINS; i += blockDim.x) lh[i] = 0.0f;
    __syncthreads();

    const int lane = threadIdx.x & 63;
    const int l    = lane & 3;
    const int grp  = lane >> 2;
    const int gw   = (blockIdx.x * blockDim.x + threadIdx.x) >> 6;
    const int nw   = (gridDim.x * blockDim.x) >> 6;
    for (int rb = gw * 16; rb < N; rb += nw * 16){
        int row = rb + grp;
        if (row < N){
            float unc, conf; bool acc;
            row_compute(logits + (size_t)row * C, labels, row, l, unc, conf, acc);
            if (l == 0) accumulate_sample(unc, conf, acc, th, lh);
        }
    }
    __syncthreads();
    for (int i = threadIdx.x; i < 4 * NBINS; i += blockDim.x)
        atomicAdd(&hist[i], (double)lh[i]);
}

// ---------- finalize: prefix/suffix sums, trapezoid AUC, loss ----------
__global__ void finalize_kernel(const double* __restrict__ hist, float* __restrict__ out){
    if (threadIdx.x == 0 && blockIdx.x == 0){
        double tau = 0.0, tiu = 0.0;
        for (int t = 0; t < NBINS; ++t){ tau += hist[1*NBINS + t]; tiu += hist[3*NBINS + t]; }
        double pac = 0.0, pau = 0.0, pic = 0.0, piu = 0.0;
        double avu_prev = 0.0, auc = 0.0;
        float th_prev = 0.0f;
        for (int t = 0; t < NTH; ++t){
            pac += hist[0*NBINS + t];  pau += hist[1*NBINS + t];
            pic += hist[2*NBINS + t];  piu += hist[3*NBINS + t];
            double nac = pac, nic = pic;
            double nau = tau - pau, niu = tiu - piu;
            double avu = (nac + niu) / (nac + nau + nic + niu + EPSD);
            float tht = (t == 20) ? 1.0f : (float)t * 0.05f;
            if (t > 0) auc += 0.5 * (avu + avu_prev) * (double)(tht - th_prev);
            avu_prev = avu; th_prev = tht;
        }
        out[1] = (float)auc;
        out[0] = (float)(-log(auc + EPSD));   // BETA = 1
    }
}

extern "C" void kernel_launch(void* const* d_in, const int* in_sizes, int n_in,
                              void* d_out, int out_size, void* d_ws, size_t ws_size,
                              hipStream_t stream) {
    const float* logits = (const float*)d_in[0];
    const int*   labels = (const int*)d_in[1];
    const int N = in_sizes[1];                 // 1048576 rows; in_sizes[0] = N*C

    // workspace layout: [0..8) minmax uints | [128..832) 88 doubles hist | [1024..) float2[N]
    unsigned* minmax = (unsigned*)d_ws;
    double*   hist   = (double*)((char*)d_ws + 128);
    float2*   uc_a   = (float2*)((char*)d_ws + 1024);
    const size_t need = 1024 + 8ull * (size_t)N;
    const bool store = (ws_size >= need);

    init_kernel<<<1, 128, 0, stream>>>(minmax, hist);
    if (store){
        pass1_kernel<true><<<2048, 256, 0, stream>>>(logits, labels, uc_a, minmax, N);
        pass2_store_kernel<<<2048, 256, 0, stream>>>(uc_a, minmax, hist, N);
    } else {
        pass1_kernel<false><<<2048, 256, 0, stream>>>(logits, labels, nullptr, minmax, N);
        pass2_recompute_kernel<<<2048, 256, 0, stream>>>(logits, labels, minmax, hist, N);
    }
    finalize_kernel<<<1, 64, 0, stream>>>(hist, (float*)d_out);
}

// Round 4
// 575.128 us; speedup vs baseline: 1.0528x; 1.0528x over previous
//
#include <hip/hip_runtime.h>
#include <math.h>

#define C 100
#define NTH 21
#define NBINS 22           // bin 21 = "never certain"
#define EPSD 1e-10

// ---------- order-preserving float<->uint encoding for atomic min/max ----------
__device__ __forceinline__ unsigned enc_f(float x){
    unsigned u = __float_as_uint(x);
    return (u & 0x80000000u) ? ~u : (u | 0x80000000u);
}
__device__ __forceinline__ float dec_f(unsigned e){
    unsigned u = (e & 0x80000000u) ? (e ^ 0x80000000u) : ~e;
    return __uint_as_float(u);
}

// ---------- per-row softmax stats; 4 lanes (l=0..3) cooperate on one row ----------
// All 4 lanes return identical (unc, conf, m).
__device__ __forceinline__ void row_stats(const float* __restrict__ rp, int l,
                                          float& unc, float& conf, float& mx){
    const float4* rp4 = (const float4*)rp;        // 400B rows, 16B aligned
    float4 v[6];
    #pragma unroll
    for (int k = 0; k < 6; ++k) v[k] = rp4[l + 4*k];
    float4 v6;
    if (l == 0) v6 = rp4[24];                     // cols 96..99

    float m = -INFINITY;
    #pragma unroll
    for (int k = 0; k < 6; ++k)
        m = fmaxf(m, fmaxf(fmaxf(v[k].x, v[k].y), fmaxf(v[k].z, v[k].w)));
    if (l == 0)
        m = fmaxf(m, fmaxf(fmaxf(v6.x, v6.y), fmaxf(v6.z, v6.w)));
    m = fmaxf(m, __shfl_xor(m, 1, 64));
    m = fmaxf(m, __shfl_xor(m, 2, 64));

    float s = 0.0f, dd = 0.0f;
    #pragma unroll
    for (int k = 0; k < 6; ++k){
        float d0 = v[k].x - m, d1 = v[k].y - m, d2 = v[k].z - m, d3 = v[k].w - m;
        float e0 = __expf(d0), e1 = __expf(d1), e2 = __expf(d2), e3 = __expf(d3);
        s  += (e0 + e1) + (e2 + e3);
        dd += (e0*d0 + e1*d1) + (e2*d2 + e3*d3);
    }
    if (l == 0){
        float d0 = v6.x - m, d1 = v6.y - m, d2 = v6.z - m, d3 = v6.w - m;
        float e0 = __expf(d0), e1 = __expf(d1), e2 = __expf(d2), e3 = __expf(d3);
        s  += (e0 + e1) + (e2 + e3);
        dd += (e0*d0 + e1*d1) + (e2*d2 + e3*d3);
    }
    s  += __shfl_xor(s, 1, 64);   dd += __shfl_xor(dd, 1, 64);
    s  += __shfl_xor(s, 2, 64);   dd += __shfl_xor(dd, 2, 64);

    conf = 1.0f / s;                 // max prob = exp(0)/S
    unc  = __logf(s) - dd / s;       // == -sum p*log(p); eps term ~1e-8, negligible
    mx   = m;
}

// ---------- init: zero hist, set min/max identities ----------
__global__ void init_kernel(unsigned* __restrict__ minmax, double* __restrict__ hist){
    if (threadIdx.x == 0){ minmax[0] = 0xFFFFFFFFu; minmax[1] = 0u; }
    if (threadIdx.x < 4*NBINS) hist[threadIdx.x] = 0.0;
}

// ---------- pass 1: stream logits; per-sample {unc, signed conf}; global min/max ----------
__global__ void __launch_bounds__(256) pass1_kernel(const float* __restrict__ logits,
        const int* __restrict__ labels, float2* __restrict__ uc_out,
        unsigned* __restrict__ minmax, int N){
    const int lane = threadIdx.x & 63;
    const int l    = lane & 3;
    const int grp  = lane >> 2;                 // 0..15: 16 rows per wave-iteration
    const int wid  = threadIdx.x >> 6;
    const int gw   = (blockIdx.x * blockDim.x + threadIdx.x) >> 6;
    const int nw   = (gridDim.x * blockDim.x) >> 6;
    const int rowstep = nw * 16;

    float rmin = INFINITY, rmax = -INFINITY;
    for (int row = gw * 16 + grp; row < N; row += rowstep){
        const float* rp = logits + (size_t)row * C;
        float unc, conf, m;
        row_stats(rp, l, unc, conf, m);
        rmin = fminf(rmin, unc);
        rmax = fmaxf(rmax, unc);
        if (l == 0){
            bool acc = (rp[labels[row]] == m);   // accurate <=> label's logit is the max
            uc_out[row] = make_float2(unc, acc ? conf : -conf);  // sign encodes accuracy
        }
    }
    #pragma unroll
    for (int off = 1; off < 64; off <<= 1){
        rmin = fminf(rmin, __shfl_xor(rmin, off, 64));
        rmax = fmaxf(rmax, __shfl_xor(rmax, off, 64));
    }
    __shared__ float smin[4], smax[4];
    if (lane == 0){ smin[wid] = rmin; smax[wid] = rmax; }
    __syncthreads();
    if (threadIdx.x == 0){
        atomicMin(minmax + 0, enc_f(fminf(fminf(smin[0], smin[1]), fminf(smin[2], smin[3]))));
        atomicMax(minmax + 1, enc_f(fmaxf(fmaxf(smax[0], smax[1]), fmaxf(smax[2], smax[3]))));
    }
}

// ---------- bucket/weight accumulation into LDS hist ----------
__device__ __forceinline__ void accumulate_sample(float unc, float conf, bool acc,
                                                  const float* __restrict__ th,
                                                  float* __restrict__ lh){
    // tanh(u) = 1 - 2/(e^{2u}+1); u >= 0 so no overflow
    float tn = 1.0f - 2.0f / (__expf(2.0f * unc) + 1.0f);
    int cnt = 0;
    #pragma unroll
    for (int t = 0; t < NTH; ++t) cnt += (unc <= th[t]) ? 1 : 0;
    int t0 = NTH - cnt;                 // 21 => never certain
    float wcert, wunc; int base;
    if (acc){ wcert = conf * (1.0f - tn);  wunc = conf * tn;  base = 0; }
    else    { float ic = 1.0f - conf;
              wcert = ic * (1.0f - tn);    wunc = ic * tn;    base = 2; }
    atomicAdd(&lh[base * NBINS + t0], wcert);        // ac or ic (certain side, prefix)
    atomicAdd(&lh[(base + 1) * NBINS + t0], wunc);   // au or iu (uncertain side, suffix)
}

// ---------- pass 2: read packed scalars, build histogram ----------
__global__ void __launch_bounds__(256) pass2_store_kernel(const float2* __restrict__ uc_in,
        const unsigned* __restrict__ minmax, double* __restrict__ hist, int N){
    __shared__ float th[NTH];
    __shared__ float lh[4 * NBINS];
    float umin = dec_f(minmax[0]);
    float umax = dec_f(minmax[1]);
    if (threadIdx.x < NTH){
        float t = (threadIdx.x == 20) ? 1.0f : (float)threadIdx.x * 0.05f;  // linspace(0,1,21)
        th[threadIdx.x] = umin + t * (umax - umin);
    }
    for (int i = threadIdx.x; i < 4 * NBINS; i += blockDim.x) lh[i] = 0.0f;
    __syncthreads();

    int stride = gridDim.x * blockDim.x;
    for (int i = blockIdx.x * blockDim.x + threadIdx.x; i < N; i += stride){
        float2 s = uc_in[i];
        accumulate_sample(s.x, fabsf(s.y), s.y > 0.0f, th, lh);
    }
    __syncthreads();
    for (int i = threadIdx.x; i < 4 * NBINS; i += blockDim.x)
        atomicAdd(&hist[i], (double)lh[i]);
}

// ---------- finalize: prefix/suffix sums, trapezoid AUC, loss ----------
__global__ void finalize_kernel(const double* __restrict__ hist, float* __restrict__ out){
    if (threadIdx.x == 0 && blockIdx.x == 0){
        double tau = 0.0, tiu = 0.0;
        for (int t = 0; t < NBINS; ++t){ tau += hist[1*NBINS + t]; tiu += hist[3*NBINS + t]; }
        double pac = 0.0, pau = 0.0, pic = 0.0, piu = 0.0;
        double avu_prev = 0.0, auc = 0.0;
        float th_prev = 0.0f;
        for (int t = 0; t < NTH; ++t){
            pac += hist[0*NBINS + t];  pau += hist[1*NBINS + t];
            pic += hist[2*NBINS + t];  piu += hist[3*NBINS + t];
            double nac = pac, nic = pic;
            double nau = tau - pau, niu = tiu - piu;
            double avu = (nac + niu) / (nac + nau + nic + niu + EPSD);
            float tht = (t == 20) ? 1.0f : (float)t * 0.05f;
            if (t > 0) auc += 0.5 * (avu + avu_prev) * (double)(tht - th_prev);
            avu_prev = avu; th_prev = tht;
        }
        out[1] = (float)auc;
        out[0] = (float)(-log(auc + EPSD));   // BETA = 1
    }
}

extern "C" void kernel_launch(void* const* d_in, const int* in_sizes, int n_in,
                              void* d_out, int out_size, void* d_ws, size_t ws_size,
                              hipStream_t stream) {
    const float* logits = (const float*)d_in[0];
    const int*   labels = (const int*)d_in[1];
    const int N = in_sizes[1];                 // 1048576 rows; in_sizes[0] = N*C

    // workspace: [0..8) minmax uints | [128..832) 88 doubles hist | [1024..) float2[N]
    unsigned* minmax = (unsigned*)d_ws;
    double*   hist   = (double*)((char*)d_ws + 128);
    float2*   uc_a   = (float2*)((char*)d_ws + 1024);

    init_kernel<<<1, 128, 0, stream>>>(minmax, hist);
    pass1_kernel<<<2048, 256, 0, stream>>>(logits, labels, uc_a, minmax, N);
    // 256 blocks: 8x less serialization on the 88 global double-atomics vs 2048,
    // while 65k threads still stream the 8 MB scalar array at full BW.
    pass2_store_kernel<<<256, 256, 0, stream>>>(uc_a, minmax, hist, N);
    finalize_kernel<<<1, 64, 0, stream>>>(hist, (float*)d_out);
}